// Round 14
// baseline (193.205 us; speedup 1.0000x reference)
//
#include <hip/hip_runtime.h>
#include <cmath>

#define IMG_H 512
#define IMG_W 512
#define TH 32            // tile rows per block (processed as 2 halves of 16)
#define HH 16            // half-tile rows
#define TW 64            // tile cols
#define LDSW 75          // ODD element stride (load-bearing!); 74 used cols + 1 pad
#define NPLANES 96       // 32 batch * 3 channels
#define NPIX 25165824.0  // 96*512*512

typedef float vf2 __attribute__((ext_vector_type(2)));

struct GaussW { float w[11]; };

// 4-array algebraic form (round 11): convolve (A,B) and (T,S), T = a^2+b^2.
// Round 14: phase 2 is ROW-LOCAL, so process the 32-row tile as two
// sequential 16-row halves sharing ONE 16-row LDS buffer:
//   LDS 38.4 -> 19.2 KB -> 8 blocks/CU (32 waves, 100% nominal occupancy)
// to close the remaining ~20us latency-stall term. Cost: vertical halo paid
// twice (+14% ph1 loads, L2-hot) and 4 cols/thread in ph2 (+DS issue).
__global__ __launch_bounds__(256, 8) void ssim_main(
    const float* __restrict__ img1, const float* __restrict__ img2,
    float* __restrict__ partials, GaussW gw, int use_atomic, float* __restrict__ out)
{
    __shared__ vf2 VAB[HH][LDSW];   // 9600 B
    __shared__ vf2 VTS[HH][LDSW];   // 9600 B  (total 19.2 KB -> 8 blocks/CU)
    __shared__ float wsum[4];

    const int tid = threadIdx.x;
    const int plane = blockIdx.z;
    const int tr0 = blockIdx.y * TH;
    const int tc0 = blockIdx.x * TW;
    const float* __restrict__ plane1 = img1 + ((size_t)plane << 18);  // uniform -> SGPR base
    const float* __restrict__ plane2 = img2 + ((size_t)plane << 18);

    float lsum = 0.f;

    for (int half = 0; half < 2; ++half) {
        const int hr0 = tr0 + half * HH;   // first output row of this half

        // ------------- Phase 1: vertical conv, packed accumulator scatter -----
        // 148 active threads: col j (gc = tc0 + j - 5), 2 chunks x 8 rows.
        // Register-stage all 36 loads first (round-13 win), single code path.
        {
            const int j = tid % 74;
            const int chunk = tid / 74;    // 0..3; active if chunk<2
            if (chunk < 2) {
                const int r0 = chunk * 8;
                const int gc = tc0 + j - 5;
                const float cmask = ((unsigned)gc < IMG_W) ? 1.f : 0.f;
                const int gcc = min(max(gc, 0), IMG_W - 1);   // v_med3

                float ra[18], rb[18];
                #pragma unroll
                for (int ii = 0; ii < 18; ++ii) {
                    const int gr = hr0 + r0 - 5 + ii;
                    const int grc = min(max(gr, 0), IMG_H - 1);
                    const uint32_t idx = (uint32_t)(grc * IMG_W + gcc);
                    ra[ii] = plane1[idx];
                    rb[ii] = plane2[idx];
                }
                __builtin_amdgcn_sched_barrier(0);   // pin load cluster first

                vf2 aAB[8], aTS[8];
                #pragma unroll
                for (int ii = 0; ii < 18; ++ii) {
                    const int gr = hr0 + r0 - 5 + ii;
                    const float rmask = ((unsigned)gr < IMG_H) ? cmask : 0.f;
                    const float a = ra[ii] * rmask;
                    const float b = rb[ii] * rmask;
                    const vf2 ab = { a, b };
                    const vf2 pq = ab * ab;                    // v_pk_mul_f32
                    const vf2 ts = { pq.x + pq.y, a * b };     // (a^2+b^2, a*b)
                    #pragma unroll
                    for (int o = 0; o < 8; ++o) {
                        if (o <= ii && ii <= o + 10) {          // compile-time
                            const float wt = gw.w[ii - o];
                            const vf2 wtv = { wt, wt };
                            if (ii == o) {                       // first touch
                                aAB[o] = wtv * ab;
                                aTS[o] = wtv * ts;
                            } else {
                                aAB[o] = __builtin_elementwise_fma(wtv, ab, aAB[o]);
                                aTS[o] = __builtin_elementwise_fma(wtv, ts, aTS[o]);
                            }
                        }
                    }
                }
                #pragma unroll
                for (int o = 0; o < 8; ++o) {
                    VAB[r0 + o][j] = aAB[o];        // ds_write_b64
                    VTS[r0 + o][j] = aTS[o];        // ds_write_b64
                }
            }
        }
        __syncthreads();

        // ------------- Phase 2: horizontal conv, packed per-column scatter ----
        // 256 threads: r = tid&15 (LOW bits -> bank-free with odd stride),
        // 16 col groups of 4. b64 pair (75r + c0 + k) mod 16: r spans 16 with
        // odd multiplier -> all 16 pairs, x4 over the wave = hw minimum.
        {
            const int r = tid & 15;
            const int c0 = (tid >> 4) * 4;
            const vf2* __restrict__ bAB = &VAB[r][c0];
            const vf2* __restrict__ bTS = &VTS[r][c0];

            vf2 mAB[4], eTS[4];

            #pragma unroll
            for (int k = 0; k <= 13; ++k) {          // stored cols c0 .. c0+13
                const vf2 vab = bAB[k];              // ds_read_b64, imm offset
                const vf2 vts = bTS[k];
                #pragma unroll
                for (int c = 0; c < 4; ++c) {
                    if (k - 10 <= c && c <= k) {                // compile-time
                        const float wt = gw.w[k - c];
                        const vf2 wtv = { wt, wt };
                        if (k == c) {                            // first touch
                            mAB[c] = wtv * vab;
                            eTS[c] = wtv * vts;
                        } else {
                            mAB[c] = __builtin_elementwise_fma(wtv, vab, mAB[c]);
                            eTS[c] = __builtin_elementwise_fma(wtv, vts, eTS[c]);
                        }
                    }
                }
            }
            #pragma unroll
            for (int c = 0; c < 4; ++c) {
                const float a1 = mAB[c].x, a2 = mAB[c].y;   // mu1, mu2
                const float T  = eTS[c].x, S = eTS[c].y;    // conv(a^2+b^2), conv(ab)
                const float h    = fmaf(a1, a1, a2 * a2);   // mu11 + mu22
                const float mu12 = a1 * a2;
                const float num  = fmaf(2.f, mu12, 0.0001f)
                                 * fmaf(2.f, S - mu12, 0.0009f);
                const float den  = (h + 0.0001f) * ((T - h) + 0.0009f);
                lsum = fmaf(num, __builtin_amdgcn_rcpf(den), lsum); // rcp ~1ulp
            }
        }
        __syncthreads();   // protect LDS before next half's phase 1 overwrite
    }

    // block reduction
    #pragma unroll
    for (int off = 32; off; off >>= 1) lsum += __shfl_down(lsum, off, 64);
    if ((tid & 63) == 0) wsum[tid >> 6] = lsum;
    __syncthreads();
    if (tid == 0) {
        const float bs = wsum[0] + wsum[1] + wsum[2] + wsum[3];
        if (use_atomic) {
            atomicAdd(out, bs * (float)(1.0 / NPIX));
        } else {
            const int bId = (blockIdx.z * gridDim.y + blockIdx.y) * gridDim.x + blockIdx.x;
            partials[bId] = bs;
        }
    }
}

__global__ __launch_bounds__(256) void ssim_reduce(
    const float* __restrict__ partials, int n, float* __restrict__ out)
{
    const int tid = threadIdx.x;
    double s = 0.0;
    for (int i = tid; i < n; i += 256) s += (double)partials[i];
    #pragma unroll
    for (int off = 32; off; off >>= 1) s += __shfl_down(s, off, 64);
    __shared__ double ws[4];
    if ((tid & 63) == 0) ws[tid >> 6] = s;
    __syncthreads();
    if (tid == 0) out[0] = (float)(((ws[0] + ws[1]) + (ws[2] + ws[3])) / NPIX);
}

extern "C" void kernel_launch(void* const* d_in, const int* in_sizes, int n_in,
                              void* d_out, int out_size, void* d_ws, size_t ws_size,
                              hipStream_t stream) {
    const float* img1 = (const float*)d_in[0];
    const float* img2 = (const float*)d_in[1];
    float* out = (float*)d_out;

    // Gaussian window (host, double precision, normalized)
    GaussW gw;
    {
        double g[11], sum = 0.0;
        for (int i = 0; i < 11; ++i) {
            const double c = (double)(i - 5);
            g[i] = std::exp(-(c * c) / 4.5);   // 2*sigma^2 = 4.5
            sum += g[i];
        }
        for (int i = 0; i < 11; ++i) gw.w[i] = (float)(g[i] / sum);
    }

    dim3 grid(IMG_W / TW, IMG_H / TH, NPLANES);   // 8 x 16 x 96 = 12288
    const int nPart = grid.x * grid.y * grid.z;

    if (ws_size >= (size_t)nPart * sizeof(float)) {
        // deterministic two-stage reduction
        ssim_main<<<grid, 256, 0, stream>>>(img1, img2, (float*)d_ws, gw, 0, out);
        ssim_reduce<<<1, 256, 0, stream>>>((float*)d_ws, nPart, out);
    } else {
        // fallback: atomic accumulation (still within tolerance)
        hipMemsetAsync(d_out, 0, sizeof(float), stream);
        ssim_main<<<grid, 256, 0, stream>>>(img1, img2, nullptr, gw, 1, out);
    }
}

// Round 15
// 131.187 us; speedup vs baseline: 1.4727x; 1.4727x over previous
//
#include <hip/hip_runtime.h>
#include <cmath>

#define IMG_H 512
#define IMG_W 512
#define TH 32            // tile rows per block (processed as 2 halves of 16)
#define HH 16            // half-tile rows
#define TW 64            // tile cols
#define LDSW 75          // ODD element stride (load-bearing!); 74 used cols + 1 pad
#define NPLANES 96       // 32 batch * 3 channels
#define NPIX 25165824.0  // 96*512*512

typedef float vf2 __attribute__((ext_vector_type(2)));

struct GaussW { float w[11]; };

// 4-array algebraic form (round 11): convolve (A,B) and (T,S), T = a^2+b^2.
// Round 15: keep round-14's half-tile geometry (19.2 KB LDS -> 8 blocks/CU,
// 32 waves) but DROP the register staging: under the 64-VGPR cap the staged
// ra[18]/rb[18] spilled to scratch (WRITE_SIZE 0.38->288 MB, the whole
// regression). At 32 waves/CU, TLP hides load latency without ILP staging.
__global__ __launch_bounds__(256, 8) void ssim_main(
    const float* __restrict__ img1, const float* __restrict__ img2,
    float* __restrict__ partials, GaussW gw, int use_atomic, float* __restrict__ out)
{
    __shared__ vf2 VAB[HH][LDSW];   // 9600 B
    __shared__ vf2 VTS[HH][LDSW];   // 9600 B  (total 19.2 KB -> 8 blocks/CU)
    __shared__ float wsum[4];

    const int tid = threadIdx.x;
    const int plane = blockIdx.z;
    const int tr0 = blockIdx.y * TH;
    const int tc0 = blockIdx.x * TW;
    const float* __restrict__ plane1 = img1 + ((size_t)plane << 18);  // uniform -> SGPR base
    const float* __restrict__ plane2 = img2 + ((size_t)plane << 18);

    float lsum = 0.f;

    for (int half = 0; half < 2; ++half) {
        const int hr0 = tr0 + half * HH;   // first output row of this half

        // ------------- Phase 1: vertical conv, packed accumulator scatter -----
        // 148 active threads: col j (gc = tc0 + j - 5), 2 chunks x 8 rows.
        // Direct loads (no staging -- VGPR cap 64), single code path,
        // first-touch accumulator init.
        {
            const int j = tid % 74;
            const int chunk = tid / 74;    // 0..3; active if chunk<2
            if (chunk < 2) {
                const int r0 = chunk * 8;
                const int gc = tc0 + j - 5;
                const float cmask = ((unsigned)gc < IMG_W) ? 1.f : 0.f;
                const int gcc = min(max(gc, 0), IMG_W - 1);   // v_med3

                vf2 aAB[8], aTS[8];    // 32 acc dwords -- fits under 64-VGPR cap
                #pragma unroll
                for (int ii = 0; ii < 18; ++ii) {
                    const int gr = hr0 + r0 - 5 + ii;
                    const float rmask = ((unsigned)gr < IMG_H) ? cmask : 0.f;
                    const int grc = min(max(gr, 0), IMG_H - 1);
                    const uint32_t idx = (uint32_t)(grc * IMG_W + gcc);
                    const float a = plane1[idx] * rmask;
                    const float b = plane2[idx] * rmask;
                    const vf2 ab = { a, b };
                    const vf2 pq = ab * ab;                    // v_pk_mul_f32
                    const vf2 ts = { pq.x + pq.y, a * b };     // (a^2+b^2, a*b)
                    #pragma unroll
                    for (int o = 0; o < 8; ++o) {
                        if (o <= ii && ii <= o + 10) {          // compile-time
                            const float wt = gw.w[ii - o];
                            const vf2 wtv = { wt, wt };
                            if (ii == o) {                       // first touch
                                aAB[o] = wtv * ab;
                                aTS[o] = wtv * ts;
                            } else {
                                aAB[o] = __builtin_elementwise_fma(wtv, ab, aAB[o]);
                                aTS[o] = __builtin_elementwise_fma(wtv, ts, aTS[o]);
                            }
                        }
                    }
                }
                #pragma unroll
                for (int o = 0; o < 8; ++o) {
                    VAB[r0 + o][j] = aAB[o];        // ds_write_b64
                    VTS[r0 + o][j] = aTS[o];        // ds_write_b64
                }
            }
        }
        __syncthreads();

        // ------------- Phase 2: horizontal conv, packed per-column scatter ----
        // 256 threads: r = tid&15 (LOW bits -> bank-spread with odd stride),
        // 16 col groups of 4 outputs.
        {
            const int r = tid & 15;
            const int c0 = (tid >> 4) * 4;
            const vf2* __restrict__ bAB = &VAB[r][c0];
            const vf2* __restrict__ bTS = &VTS[r][c0];

            vf2 mAB[4], eTS[4];

            #pragma unroll
            for (int k = 0; k <= 13; ++k) {          // stored cols c0 .. c0+13
                const vf2 vab = bAB[k];              // ds_read_b64, imm offset
                const vf2 vts = bTS[k];
                #pragma unroll
                for (int c = 0; c < 4; ++c) {
                    if (k - 10 <= c && c <= k) {                // compile-time
                        const float wt = gw.w[k - c];
                        const vf2 wtv = { wt, wt };
                        if (k == c) {                            // first touch
                            mAB[c] = wtv * vab;
                            eTS[c] = wtv * vts;
                        } else {
                            mAB[c] = __builtin_elementwise_fma(wtv, vab, mAB[c]);
                            eTS[c] = __builtin_elementwise_fma(wtv, vts, eTS[c]);
                        }
                    }
                }
            }
            #pragma unroll
            for (int c = 0; c < 4; ++c) {
                const float a1 = mAB[c].x, a2 = mAB[c].y;   // mu1, mu2
                const float T  = eTS[c].x, S = eTS[c].y;    // conv(a^2+b^2), conv(ab)
                const float h    = fmaf(a1, a1, a2 * a2);   // mu11 + mu22
                const float mu12 = a1 * a2;
                const float num  = fmaf(2.f, mu12, 0.0001f)
                                 * fmaf(2.f, S - mu12, 0.0009f);
                const float den  = (h + 0.0001f) * ((T - h) + 0.0009f);
                lsum = fmaf(num, __builtin_amdgcn_rcpf(den), lsum); // rcp ~1ulp
            }
        }
        __syncthreads();   // protect LDS before next half's phase 1 overwrite
    }

    // block reduction
    #pragma unroll
    for (int off = 32; off; off >>= 1) lsum += __shfl_down(lsum, off, 64);
    if ((tid & 63) == 0) wsum[tid >> 6] = lsum;
    __syncthreads();
    if (tid == 0) {
        const float bs = wsum[0] + wsum[1] + wsum[2] + wsum[3];
        if (use_atomic) {
            atomicAdd(out, bs * (float)(1.0 / NPIX));
        } else {
            const int bId = (blockIdx.z * gridDim.y + blockIdx.y) * gridDim.x + blockIdx.x;
            partials[bId] = bs;
        }
    }
}

__global__ __launch_bounds__(256) void ssim_reduce(
    const float* __restrict__ partials, int n, float* __restrict__ out)
{
    const int tid = threadIdx.x;
    double s = 0.0;
    for (int i = tid; i < n; i += 256) s += (double)partials[i];
    #pragma unroll
    for (int off = 32; off; off >>= 1) s += __shfl_down(s, off, 64);
    __shared__ double ws[4];
    if ((tid & 63) == 0) ws[tid >> 6] = s;
    __syncthreads();
    if (tid == 0) out[0] = (float)(((ws[0] + ws[1]) + (ws[2] + ws[3])) / NPIX);
}

extern "C" void kernel_launch(void* const* d_in, const int* in_sizes, int n_in,
                              void* d_out, int out_size, void* d_ws, size_t ws_size,
                              hipStream_t stream) {
    const float* img1 = (const float*)d_in[0];
    const float* img2 = (const float*)d_in[1];
    float* out = (float*)d_out;

    // Gaussian window (host, double precision, normalized)
    GaussW gw;
    {
        double g[11], sum = 0.0;
        for (int i = 0; i < 11; ++i) {
            const double c = (double)(i - 5);
            g[i] = std::exp(-(c * c) / 4.5);   // 2*sigma^2 = 4.5
            sum += g[i];
        }
        for (int i = 0; i < 11; ++i) gw.w[i] = (float)(g[i] / sum);
    }

    dim3 grid(IMG_W / TW, IMG_H / TH, NPLANES);   // 8 x 16 x 96 = 12288
    const int nPart = grid.x * grid.y * grid.z;

    if (ws_size >= (size_t)nPart * sizeof(float)) {
        // deterministic two-stage reduction
        ssim_main<<<grid, 256, 0, stream>>>(img1, img2, (float*)d_ws, gw, 0, out);
        ssim_reduce<<<1, 256, 0, stream>>>((float*)d_ws, nPart, out);
    } else {
        // fallback: atomic accumulation (still within tolerance)
        hipMemsetAsync(d_out, 0, sizeof(float), stream);
        ssim_main<<<grid, 256, 0, stream>>>(img1, img2, nullptr, gw, 1, out);
    }
}

// Round 16
// 130.976 us; speedup vs baseline: 1.4751x; 1.0016x over previous
//
#include <hip/hip_runtime.h>
#include <cmath>

#define IMG_H 512
#define IMG_W 512
#define TH 32            // tile rows per block (processed as 2 halves of 16)
#define HH 16            // half-tile rows
#define TW 64            // tile cols
#define LDSW 75          // ODD element stride (load-bearing!); 74 used cols + 1 pad
#define NPLANES 96       // 32 batch * 3 channels
#define NPIX 25165824.0  // 96*512*512

typedef float vf2 __attribute__((ext_vector_type(2)));

struct GaussW { float w[11]; };

// 4-array algebraic form (round 11): convolve (A,B) and (T,S), T = a^2+b^2.
// Round 16: half-tile LDS (19.2 KB) + __launch_bounds__(256,6):
//   - 6 blocks/CU = 24 waves (75% nominal) -- between round 13 (16 waves,
//     ~20us stall) and round 15 (32 waves, but 64-VGPR cap broke codegen)
//   - VGPR ceiling 85 > the body's natural 52 -> no remat (round 15:
//     VGPR 28, FETCH +47%), no spill (round 14: WRITE 288 MB).
__global__ __launch_bounds__(256, 6) void ssim_main(
    const float* __restrict__ img1, const float* __restrict__ img2,
    float* __restrict__ partials, GaussW gw, int use_atomic, float* __restrict__ out)
{
    __shared__ vf2 VAB[HH][LDSW];   // 9600 B
    __shared__ vf2 VTS[HH][LDSW];   // 9600 B  (total 19.2 KB)
    __shared__ float wsum[4];

    const int tid = threadIdx.x;
    const int plane = blockIdx.z;
    const int tr0 = blockIdx.y * TH;
    const int tc0 = blockIdx.x * TW;
    const float* __restrict__ plane1 = img1 + ((size_t)plane << 18);  // uniform -> SGPR base
    const float* __restrict__ plane2 = img2 + ((size_t)plane << 18);

    float lsum = 0.f;

    for (int half = 0; half < 2; ++half) {
        const int hr0 = tr0 + half * HH;   // first output row of this half

        // ------------- Phase 1: vertical conv, packed accumulator scatter -----
        // 148 active threads: col j (gc = tc0 + j - 5), 2 chunks x 8 rows.
        // Direct loads (TLP at 24 waves hides latency; no staging arrays),
        // single code path, first-touch accumulator init.
        {
            const int j = tid % 74;
            const int chunk = tid / 74;    // 0..3; active if chunk<2
            if (chunk < 2) {
                const int r0 = chunk * 8;
                const int gc = tc0 + j - 5;
                const float cmask = ((unsigned)gc < IMG_W) ? 1.f : 0.f;
                const int gcc = min(max(gc, 0), IMG_W - 1);   // v_med3

                vf2 aAB[8], aTS[8];    // 32 acc dwords
                #pragma unroll
                for (int ii = 0; ii < 18; ++ii) {
                    const int gr = hr0 + r0 - 5 + ii;
                    const float rmask = ((unsigned)gr < IMG_H) ? cmask : 0.f;
                    const int grc = min(max(gr, 0), IMG_H - 1);
                    const uint32_t idx = (uint32_t)(grc * IMG_W + gcc);
                    const float a = plane1[idx] * rmask;
                    const float b = plane2[idx] * rmask;
                    const vf2 ab = { a, b };
                    const vf2 pq = ab * ab;                    // v_pk_mul_f32
                    const vf2 ts = { pq.x + pq.y, a * b };     // (a^2+b^2, a*b)
                    #pragma unroll
                    for (int o = 0; o < 8; ++o) {
                        if (o <= ii && ii <= o + 10) {          // compile-time
                            const float wt = gw.w[ii - o];
                            const vf2 wtv = { wt, wt };
                            if (ii == o) {                       // first touch
                                aAB[o] = wtv * ab;
                                aTS[o] = wtv * ts;
                            } else {
                                aAB[o] = __builtin_elementwise_fma(wtv, ab, aAB[o]);
                                aTS[o] = __builtin_elementwise_fma(wtv, ts, aTS[o]);
                            }
                        }
                    }
                }
                #pragma unroll
                for (int o = 0; o < 8; ++o) {
                    VAB[r0 + o][j] = aAB[o];        // ds_write_b64
                    VTS[r0 + o][j] = aTS[o];        // ds_write_b64
                }
            }
        }
        __syncthreads();

        // ------------- Phase 2: horizontal conv, packed per-column scatter ----
        // 256 threads: r = tid&15 (LOW bits): b64 pair (11r + c0 + k) mod 16
        // is a bijection over r -> 16 pairs x2 per half-wave = hw minimum.
        {
            const int r = tid & 15;
            const int c0 = (tid >> 4) * 4;
            const vf2* __restrict__ bAB = &VAB[r][c0];
            const vf2* __restrict__ bTS = &VTS[r][c0];

            vf2 mAB[4], eTS[4];

            #pragma unroll
            for (int k = 0; k <= 13; ++k) {          // stored cols c0 .. c0+13
                const vf2 vab = bAB[k];              // ds_read_b64, imm offset
                const vf2 vts = bTS[k];
                #pragma unroll
                for (int c = 0; c < 4; ++c) {
                    if (k - 10 <= c && c <= k) {                // compile-time
                        const float wt = gw.w[k - c];
                        const vf2 wtv = { wt, wt };
                        if (k == c) {                            // first touch
                            mAB[c] = wtv * vab;
                            eTS[c] = wtv * vts;
                        } else {
                            mAB[c] = __builtin_elementwise_fma(wtv, vab, mAB[c]);
                            eTS[c] = __builtin_elementwise_fma(wtv, vts, eTS[c]);
                        }
                    }
                }
            }
            #pragma unroll
            for (int c = 0; c < 4; ++c) {
                const float a1 = mAB[c].x, a2 = mAB[c].y;   // mu1, mu2
                const float T  = eTS[c].x, S = eTS[c].y;    // conv(a^2+b^2), conv(ab)
                const float h    = fmaf(a1, a1, a2 * a2);   // mu11 + mu22
                const float mu12 = a1 * a2;
                const float num  = fmaf(2.f, mu12, 0.0001f)
                                 * fmaf(2.f, S - mu12, 0.0009f);
                const float den  = (h + 0.0001f) * ((T - h) + 0.0009f);
                lsum = fmaf(num, __builtin_amdgcn_rcpf(den), lsum); // rcp ~1ulp
            }
        }
        __syncthreads();   // protect LDS before next half's phase 1 overwrite
    }

    // block reduction
    #pragma unroll
    for (int off = 32; off; off >>= 1) lsum += __shfl_down(lsum, off, 64);
    if ((tid & 63) == 0) wsum[tid >> 6] = lsum;
    __syncthreads();
    if (tid == 0) {
        const float bs = wsum[0] + wsum[1] + wsum[2] + wsum[3];
        if (use_atomic) {
            atomicAdd(out, bs * (float)(1.0 / NPIX));
        } else {
            const int bId = (blockIdx.z * gridDim.y + blockIdx.y) * gridDim.x + blockIdx.x;
            partials[bId] = bs;
        }
    }
}

__global__ __launch_bounds__(256) void ssim_reduce(
    const float* __restrict__ partials, int n, float* __restrict__ out)
{
    const int tid = threadIdx.x;
    double s = 0.0;
    for (int i = tid; i < n; i += 256) s += (double)partials[i];
    #pragma unroll
    for (int off = 32; off; off >>= 1) s += __shfl_down(s, off, 64);
    __shared__ double ws[4];
    if ((tid & 63) == 0) ws[tid >> 6] = s;
    __syncthreads();
    if (tid == 0) out[0] = (float)(((ws[0] + ws[1]) + (ws[2] + ws[3])) / NPIX);
}

extern "C" void kernel_launch(void* const* d_in, const int* in_sizes, int n_in,
                              void* d_out, int out_size, void* d_ws, size_t ws_size,
                              hipStream_t stream) {
    const float* img1 = (const float*)d_in[0];
    const float* img2 = (const float*)d_in[1];
    float* out = (float*)d_out;

    // Gaussian window (host, double precision, normalized)
    GaussW gw;
    {
        double g[11], sum = 0.0;
        for (int i = 0; i < 11; ++i) {
            const double c = (double)(i - 5);
            g[i] = std::exp(-(c * c) / 4.5);   // 2*sigma^2 = 4.5
            sum += g[i];
        }
        for (int i = 0; i < 11; ++i) gw.w[i] = (float)(g[i] / sum);
    }

    dim3 grid(IMG_W / TW, IMG_H / TH, NPLANES);   // 8 x 16 x 96 = 12288
    const int nPart = grid.x * grid.y * grid.z;

    if (ws_size >= (size_t)nPart * sizeof(float)) {
        // deterministic two-stage reduction
        ssim_main<<<grid, 256, 0, stream>>>(img1, img2, (float*)d_ws, gw, 0, out);
        ssim_reduce<<<1, 256, 0, stream>>>((float*)d_ws, nPart, out);
    } else {
        // fallback: atomic accumulation (still within tolerance)
        hipMemsetAsync(d_out, 0, sizeof(float), stream);
        ssim_main<<<grid, 256, 0, stream>>>(img1, img2, nullptr, gw, 1, out);
    }
}

// Round 17
// 106.132 us; speedup vs baseline: 1.8204x; 1.2341x over previous
//
#include <hip/hip_runtime.h>
#include <cmath>

#define IMG_H 512
#define IMG_W 512
#define TH 32            // tile rows
#define TW 64            // tile cols
#define LDSW 75          // ODD element stride (load-bearing); 74 used cols + 1 pad
#define NPLANES 96       // 32 batch * 3 channels
#define NPIX 25165824.0  // 96*512*512

typedef float vf2 __attribute__((ext_vector_type(2)));

struct GaussW { float w[11]; };

// 4-array algebraic form (round 11): convolve (A,B) and (T,S), T = a^2+b^2.
// Round 17: ANTI-FISSION decomposition. Evidence (r12-16): with 44 acc dwords
// the allocator (~52 VGPR) fissions the o-loop and re-issues loads per pass
// (L2-hit, invisible in FETCH) -> busy 70us vs ~26us ideal. Fix: R=4 output
// rows per task (16 acc dwords, live ~34), 592 tasks grid-strided over 256
// threads; phase 2 split into two 4-col halves (16 acc dwords each).
__global__ __launch_bounds__(256, 4) void ssim_main(
    const float* __restrict__ img1, const float* __restrict__ img2,
    float* __restrict__ partials, GaussW gw, int use_atomic, float* __restrict__ out)
{
    __shared__ vf2 VAB[TH][LDSW];   // 19200 B
    __shared__ vf2 VTS[TH][LDSW];   // 19200 B  (38.4 KB -> 4 blocks/CU)
    __shared__ float wsum[4];

    const int tid = threadIdx.x;
    const int plane = blockIdx.z;
    const int tr0 = blockIdx.y * TH;
    const int tc0 = blockIdx.x * TW;
    const float* __restrict__ plane1 = img1 + ((size_t)plane << 18);  // uniform -> SGPR base
    const float* __restrict__ plane2 = img2 + ((size_t)plane << 18);

    // ---------------- Phase 1: vertical conv, R=4 anti-fission tasks ----------
    // Task t -> (col j = t%74, rowgroup g = t/74): outputs rows 4g..4g+3,
    // inputs rows 4g-5..4g+8 (14 loads x2). Live set ~34 dwords -> single
    // clean pass, no compiler loop fission.
    for (int t = tid; t < 74 * 8; t += 256) {
        const int j = t % 74;
        const int g = t / 74;
        const int r0 = g * 4;
        const int gc = tc0 + j - 5;
        const float cmask = ((unsigned)gc < IMG_W) ? 1.f : 0.f;
        const int gcc = min(max(gc, 0), IMG_W - 1);   // v_med3

        vf2 aAB[4], aTS[4];    // 16 acc dwords
        #pragma unroll
        for (int ii = 0; ii < 14; ++ii) {
            const int gr = tr0 + r0 - 5 + ii;
            const float rmask = ((unsigned)gr < IMG_H) ? cmask : 0.f;
            const int grc = min(max(gr, 0), IMG_H - 1);
            const uint32_t idx = (uint32_t)(grc * IMG_W + gcc);
            const float a = plane1[idx] * rmask;
            const float b = plane2[idx] * rmask;
            const vf2 ab = { a, b };
            const vf2 pq = ab * ab;                    // v_pk_mul_f32
            const vf2 ts = { pq.x + pq.y, a * b };     // (a^2+b^2, a*b)
            #pragma unroll
            for (int o = 0; o < 4; ++o) {
                if (o <= ii && ii <= o + 10) {          // compile-time predicate
                    const float wt = gw.w[ii - o];
                    const vf2 wtv = { wt, wt };
                    if (ii == o) {                       // first touch
                        aAB[o] = wtv * ab;
                        aTS[o] = wtv * ts;
                    } else {
                        aAB[o] = __builtin_elementwise_fma(wtv, ab, aAB[o]);
                        aTS[o] = __builtin_elementwise_fma(wtv, ts, aTS[o]);
                    }
                }
            }
        }
        #pragma unroll
        for (int o = 0; o < 4; ++o) {
            VAB[r0 + o][j] = aAB[o];        // ds_write_b64
            VTS[r0 + o][j] = aTS[o];        // ds_write_b64
        }
    }
    __syncthreads();

    // ---------------- Phase 2: horizontal conv, two 4-col halves --------------
    // r = tid&31 (LOW bits): b64 pair (75r + c0 + k) mod 16 covers all 16
    // pairs x2 per half-wave = hw minimum. Each half: 16 acc dwords.
    float lsum = 0.f;
    {
        const int r = tid & 31;
        #pragma unroll
        for (int h = 0; h < 2; ++h) {
            const int c0 = (tid >> 5) * 8 + h * 4;
            const vf2* __restrict__ bAB = &VAB[r][c0];
            const vf2* __restrict__ bTS = &VTS[r][c0];

            vf2 mAB[4], eTS[4];
            #pragma unroll
            for (int k = 0; k <= 13; ++k) {          // stored cols c0 .. c0+13
                const vf2 vab = bAB[k];              // ds_read_b64, imm offset
                const vf2 vts = bTS[k];
                #pragma unroll
                for (int c = 0; c < 4; ++c) {
                    if (k - 10 <= c && c <= k) {                // compile-time
                        const float wt = gw.w[k - c];
                        const vf2 wtv = { wt, wt };
                        if (k == c) {                            // first touch
                            mAB[c] = wtv * vab;
                            eTS[c] = wtv * vts;
                        } else {
                            mAB[c] = __builtin_elementwise_fma(wtv, vab, mAB[c]);
                            eTS[c] = __builtin_elementwise_fma(wtv, vts, eTS[c]);
                        }
                    }
                }
            }
            #pragma unroll
            for (int c = 0; c < 4; ++c) {
                const float a1 = mAB[c].x, a2 = mAB[c].y;   // mu1, mu2
                const float T  = eTS[c].x, S = eTS[c].y;    // conv(a^2+b^2), conv(ab)
                const float hh   = fmaf(a1, a1, a2 * a2);   // mu11 + mu22
                const float mu12 = a1 * a2;
                const float num  = fmaf(2.f, mu12, 0.0001f)
                                 * fmaf(2.f, S - mu12, 0.0009f);
                const float den  = (hh + 0.0001f) * ((T - hh) + 0.0009f);
                lsum = fmaf(num, __builtin_amdgcn_rcpf(den), lsum); // rcp ~1ulp
            }
        }
    }
    // block reduction
    #pragma unroll
    for (int off = 32; off; off >>= 1) lsum += __shfl_down(lsum, off, 64);
    if ((tid & 63) == 0) wsum[tid >> 6] = lsum;
    __syncthreads();
    if (tid == 0) {
        const float bs = wsum[0] + wsum[1] + wsum[2] + wsum[3];
        if (use_atomic) {
            atomicAdd(out, bs * (float)(1.0 / NPIX));
        } else {
            const int bId = (blockIdx.z * gridDim.y + blockIdx.y) * gridDim.x + blockIdx.x;
            partials[bId] = bs;
        }
    }
}

__global__ __launch_bounds__(256) void ssim_reduce(
    const float* __restrict__ partials, int n, float* __restrict__ out)
{
    const int tid = threadIdx.x;
    double s = 0.0;
    for (int i = tid; i < n; i += 256) s += (double)partials[i];
    #pragma unroll
    for (int off = 32; off; off >>= 1) s += __shfl_down(s, off, 64);
    __shared__ double ws[4];
    if ((tid & 63) == 0) ws[tid >> 6] = s;
    __syncthreads();
    if (tid == 0) out[0] = (float)(((ws[0] + ws[1]) + (ws[2] + ws[3])) / NPIX);
}

extern "C" void kernel_launch(void* const* d_in, const int* in_sizes, int n_in,
                              void* d_out, int out_size, void* d_ws, size_t ws_size,
                              hipStream_t stream) {
    const float* img1 = (const float*)d_in[0];
    const float* img2 = (const float*)d_in[1];
    float* out = (float*)d_out;

    // Gaussian window (host, double precision, normalized)
    GaussW gw;
    {
        double g[11], sum = 0.0;
        for (int i = 0; i < 11; ++i) {
            const double c = (double)(i - 5);
            g[i] = std::exp(-(c * c) / 4.5);   // 2*sigma^2 = 4.5
            sum += g[i];
        }
        for (int i = 0; i < 11; ++i) gw.w[i] = (float)(g[i] / sum);
    }

    dim3 grid(IMG_W / TW, IMG_H / TH, NPLANES);   // 8 x 16 x 96 = 12288
    const int nPart = grid.x * grid.y * grid.z;

    if (ws_size >= (size_t)nPart * sizeof(float)) {
        // deterministic two-stage reduction
        ssim_main<<<grid, 256, 0, stream>>>(img1, img2, (float*)d_ws, gw, 0, out);
        ssim_reduce<<<1, 256, 0, stream>>>((float*)d_ws, nPart, out);
    } else {
        // fallback: atomic accumulation (still within tolerance)
        hipMemsetAsync(d_out, 0, sizeof(float), stream);
        ssim_main<<<grid, 256, 0, stream>>>(img1, img2, nullptr, gw, 1, out);
    }
}